// Round 2
// baseline (748.360 us; speedup 1.0000x reference)
//
#include <hip/hip_runtime.h>
#include <hip/hip_cooperative_groups.h>

namespace cg = cooperative_groups;

#define BATCH 16
#define NN 512   // n  (j index, "nxt" side; rows of X)
#define MM 512   // m  (i index, "cur" side; cols of X)
#define DD 128
#define QP_ITERS 20

// ---------------------------------------------------------------------------
// row_norms: rc[b*512+p] = ||nc[b,p]||^2 + ||ec[b,p]||^2
//            rn[b*512+p] = ||nn[b,p]||^2 + ||en[b,p]||^2
// ---------------------------------------------------------------------------
__global__ __launch_bounds__(64) void row_norms_kernel(
    const float* __restrict__ nc, const float* __restrict__ ec,
    const float* __restrict__ nn, const float* __restrict__ en,
    float* __restrict__ rc, float* __restrict__ rn)
{
    int row = blockIdx.x;            // b*512 + p
    int t   = threadIdx.x;           // 0..63
    size_t base = (size_t)row * DD;

    float2 a = ((const float2*)(nc + base))[t];
    float2 b = ((const float2*)(ec + base))[t];
    float vc = a.x*a.x + a.y*a.y + b.x*b.x + b.y*b.y;

    float2 c = ((const float2*)(nn + base))[t];
    float2 d = ((const float2*)(en + base))[t];
    float vn = c.x*c.x + c.y*c.y + d.x*d.x + d.y*d.y;

    #pragma unroll
    for (int off = 32; off; off >>= 1) {
        vc += __shfl_down(vc, off);
        vn += __shfl_down(vn, off);
    }
    if (t == 0) { rc[row] = vc; rn[row] = vn; }
}

// ---------------------------------------------------------------------------
// gemm_q: qm[b,j,i] = 0.5*(rc[b,i]+rn[b,j]) - (nc_i . nn_j + ec_i . en_j)
// (unchanged from R1 — passed; optimize next round)
// ---------------------------------------------------------------------------
__global__ __launch_bounds__(256) void gemm_q_kernel(
    const float* __restrict__ nc, const float* __restrict__ ec,
    const float* __restrict__ nn, const float* __restrict__ en,
    const float* __restrict__ rc, const float* __restrict__ rn,
    float* __restrict__ qm, float* __restrict__ sumq, float* __restrict__ sumq2)
{
    int b  = blockIdx.z;
    int it = blockIdx.x;   // i tile (cur), 64 wide
    int jt = blockIdx.y;   // j tile (nxt), 64 wide
    int tid = threadIdx.x;
    int tx = tid & 15, ty = tid >> 4;

    __shared__ float As[64][17];
    __shared__ float Bs[64][17];

    float acc[4][4] = {};

    const float* a0 = nn + ((size_t)b*NN + jt*64) * DD;
    const float* a1 = en + ((size_t)b*NN + jt*64) * DD;
    const float* b0 = nc + ((size_t)b*MM + it*64) * DD;
    const float* b1 = ec + ((size_t)b*MM + it*64) * DD;

    int lrow = tid >> 4;   // 0..15
    int lk   = tid & 15;   // 0..15

    for (int mat = 0; mat < 2; ++mat) {
        const float* ap = mat ? a1 : a0;
        const float* bp = mat ? b1 : b0;
        for (int kc = 0; kc < DD; kc += 16) {
            __syncthreads();
            #pragma unroll
            for (int r = 0; r < 4; ++r) {
                int row = lrow + r*16;
                As[row][lk] = ap[(size_t)row*DD + kc + lk];
                Bs[row][lk] = bp[(size_t)row*DD + kc + lk];
            }
            __syncthreads();
            #pragma unroll
            for (int k = 0; k < 16; ++k) {
                float ar[4], br[4];
                #pragma unroll
                for (int r = 0; r < 4; ++r) ar[r] = As[ty*4 + r][k];
                #pragma unroll
                for (int c = 0; c < 4; ++c) br[c] = Bs[tx*4 + c][k];
                #pragma unroll
                for (int r = 0; r < 4; ++r)
                    #pragma unroll
                    for (int c = 0; c < 4; ++c)
                        acc[r][c] += ar[r] * br[c];
            }
        }
    }

    float qs = 0.f, q2s = 0.f;
    #pragma unroll
    for (int r = 0; r < 4; ++r) {
        int j = jt*64 + ty*4 + r;
        float rnj = rn[b*NN + j];
        float4 o;
        float v;
        int i0 = it*64 + tx*4;
        v = 0.5f*(rc[b*MM + i0 + 0] + rnj) - acc[r][0]; o.x = v; qs += v; q2s += v*v;
        v = 0.5f*(rc[b*MM + i0 + 1] + rnj) - acc[r][1]; o.y = v; qs += v; q2s += v*v;
        v = 0.5f*(rc[b*MM + i0 + 2] + rnj) - acc[r][2]; o.z = v; qs += v; q2s += v*v;
        v = 0.5f*(rc[b*MM + i0 + 3] + rnj) - acc[r][3]; o.w = v; qs += v; q2s += v*v;
        *(float4*)(qm + ((size_t)b*NN + j)*MM + i0) = o;
    }

    #pragma unroll
    for (int off = 32; off; off >>= 1) {
        qs  += __shfl_down(qs,  off);
        q2s += __shfl_down(q2s, off);
    }
    __shared__ float red[8];
    int wid = tid >> 6, lane = tid & 63;
    if (lane == 0) { red[wid] = qs; red[4 + wid] = q2s; }
    __syncthreads();
    if (tid == 0) {
        atomicAdd(&sumq[b],  red[0] + red[1] + red[2] + red[3]);
        atomicAdd(&sumq2[b], red[4] + red[5] + red[6] + red[7]);
    }
}

// ---------------------------------------------------------------------------
// zero the sumq/sumq2/cbufS/cbufQ region (contiguous floats)
// ---------------------------------------------------------------------------
__global__ __launch_bounds__(1024) void zero_ws_kernel(float* __restrict__ z, int n)
{
    int idx = blockIdx.x * blockDim.x + threadIdx.x;
    if (idx < n) z[idx] = 0.f;
}

__global__ void init_scalars_kernel(const float* __restrict__ sumq,
                                    const float* __restrict__ sumq2,
                                    float* __restrict__ lrbuf, float* __restrict__ s1buf)
{
    int b = threadIdx.x;
    if (b < BATCH) {
        lrbuf[b] = 0.5f / (sumq2[b] + 1e-8f);
        s1buf[b] = sumq[b] * (1.0f / (float)MM);   // s1 = sum(qm)/m  (X0 = 1/m)
    }
}

// ---------------------------------------------------------------------------
// qp_iter_kernel: the whole 20-iteration projected-gradient solve, persistent.
// 256 blocks x 1024 threads (one block/CU, cooperative). qm and X live in
// VGPRs for the entire solve (16 elements/thread, strided column ownership
// i = cseg + 32k so LDS transposes and global accesses are conflict-free).
// Per iteration: one grid.sync(); colsum/colq accumulated via LDS column
// reduce + 512 global fp32 atomics per block into per-iteration slots
// (pre-zeroed by zero_ws_kernel — no re-zero races).
// ---------------------------------------------------------------------------
__global__ __launch_bounds__(1024, 4) void qp_iter_kernel(
    const float* __restrict__ qm, const float* __restrict__ lrbuf,
    const float* __restrict__ s1buf, float* __restrict__ cbufS,
    float* __restrict__ cbufQ, float* __restrict__ out)
{
    cg::grid_group grid = cg::this_grid();
    __shared__ float lds[32 * 512];   // exactly 64 KB

    int tid   = threadIdx.x;
    int blk   = blockIdx.x;
    int b     = blk >> 4;            // batch
    int g     = blk & 15;            // row-group: rows j0..j0+31
    int r_loc = tid >> 5;            // 0..31 local row
    int cseg  = tid & 31;            // column segment; owns cols cseg + 32k
    int j     = g * 32 + r_loc;

    const float lr = lrbuf[b];
    size_t rowbase = ((size_t)b * NN + j) * MM;

    float q[16], x[16], f[16];
    #pragma unroll
    for (int k = 0; k < 16; ++k) q[k] = qm[rowbase + cseg + 32*k];

    const float inv_m = 1.0f / (float)MM;
    #pragma unroll
    for (int k = 0; k < 16; ++k) { x[k] = inv_m; f[k] = 1.0f; }

    float s = s1buf[b];

    int i_rd = tid >> 1;             // column this thread reduces in LDS pass
    int rh   = (tid & 1) * 16;       // which 16-row half

    for (int t = 1; t <= QP_ITERS; ++t) {
        if (t > 1) {
            // f and s from previous iteration's colsum/colq (slot t-2)
            const float* csp = cbufS + (size_t)(t - 2) * (BATCH * MM) + b * MM;
            const float* cqp = cbufQ + (size_t)(t - 2) * (BATCH * MM) + b * MM;
            float local = 0.f;
            #pragma unroll
            for (int k = 0; k < 16; ++k) {
                float cs = csp[cseg + 32*k];
                float cq = cqp[cseg + 32*k];
                float fk = fminf(1.0f, 2.0f / (cs + 1e-8f));
                f[k] = fk;
                local += fk * cq;    // s = sum_i f_i * colq_i
            }
            #pragma unroll
            for (int m = 16; m; m >>= 1) local += __shfl_xor(local, m);
            s = local;
        }

        // gradient step + clip + row normalize (rows are intra-half-wave)
        float c = 2.0f * lr * s;
        float rp = 0.f;
        #pragma unroll
        for (int k = 0; k < 16; ++k) {
            float v = x[k] * f[k] - c * q[k];
            v = fminf(fmaxf(v, 0.f), 1.f);
            x[k] = v;
            rp += v;
        }
        #pragma unroll
        for (int m = 16; m; m >>= 1) rp += __shfl_xor(rp, m);
        float inv = 1.0f / (rp + 1e-8f);
        #pragma unroll
        for (int k = 0; k < 16; ++k) x[k] *= inv;

        // ---- column reduce pass 1: colsum(X2) ----
        #pragma unroll
        for (int k = 0; k < 16; ++k) lds[r_loc * 512 + cseg + 32*k] = x[k];
        __syncthreads();
        float cs = 0.f;
        #pragma unroll
        for (int r = 0; r < 16; ++r) cs += lds[(rh + r) * 512 + i_rd];
        cs += __shfl_xor(cs, 1);
        if ((tid & 1) == 0)
            atomicAdd(cbufS + (size_t)(t - 1) * (BATCH * MM) + b * MM + i_rd, cs);
        __syncthreads();

        // ---- column reduce pass 2: colq = colsum(qm * X2) ----
        #pragma unroll
        for (int k = 0; k < 16; ++k) lds[r_loc * 512 + cseg + 32*k] = q[k] * x[k];
        __syncthreads();
        float cq = 0.f;
        #pragma unroll
        for (int r = 0; r < 16; ++r) cq += lds[(rh + r) * 512 + i_rd];
        cq += __shfl_xor(cq, 1);
        if ((tid & 1) == 0)
            atomicAdd(cbufQ + (size_t)(t - 1) * (BATCH * MM) + b * MM + i_rd, cq);

        grid.sync();
    }

    // final lazy column scale from iteration 20's colsum (slot 19)
    const float* csp = cbufS + (size_t)(QP_ITERS - 1) * (BATCH * MM) + b * MM;
    #pragma unroll
    for (int k = 0; k < 16; ++k) {
        float cs = csp[cseg + 32*k];
        float fk = fminf(1.0f, 2.0f / (cs + 1e-8f));
        out[rowbase + cseg + 32*k] = x[k] * fk;
    }
}

// ---------------------------------------------------------------------------
extern "C" void kernel_launch(void* const* d_in, const int* in_sizes, int n_in,
                              void* d_out, int out_size, void* d_ws, size_t ws_size,
                              hipStream_t stream)
{
    const float* nc = (const float*)d_in[0];  // n_emb_cur (16,512,128)
    const float* ec = (const float*)d_in[1];  // e_emb_cur
    const float* nn = (const float*)d_in[2];  // n_emb_nxt
    const float* en = (const float*)d_in[3];  // e_emb_nxt
    float* out = (float*)d_out;               // (16, 512*512) fp32

    float* ws = (float*)d_ws;
    const size_t QM_FLOATS = (size_t)BATCH * NN * MM;       // 4,194,304

    float* qm    = ws;
    // contiguous zero region: sumq, sumq2, cbufS, cbufQ
    float* zreg  = ws + QM_FLOATS;
    float* sumq  = zreg;                                    // 16
    float* sumq2 = zreg + 16;                               // 16
    float* cbufS = zreg + 32;                               // 20*16*512
    float* cbufQ = cbufS + (size_t)QP_ITERS * BATCH * MM;
    const int ZN = 32 + 2 * QP_ITERS * BATCH * MM;          // 327,712 floats
    float* rc    = cbufQ + (size_t)QP_ITERS * BATCH * MM;   // 8192
    float* rn    = rc + BATCH * MM;                         // 8192
    float* lrbuf = rn + BATCH * NN;                         // 16
    float* s1buf = lrbuf + 16;                              // 16

    zero_ws_kernel<<<(ZN + 1023) / 1024, 1024, 0, stream>>>(zreg, ZN);
    row_norms_kernel<<<BATCH * 512, 64, 0, stream>>>(nc, ec, nn, en, rc, rn);
    gemm_q_kernel<<<dim3(8, 8, BATCH), 256, 0, stream>>>(nc, ec, nn, en, rc, rn,
                                                         qm, sumq, sumq2);
    init_scalars_kernel<<<1, 64, 0, stream>>>(sumq, sumq2, lrbuf, s1buf);

    void* args[] = { (void*)&qm, (void*)&lrbuf, (void*)&s1buf,
                     (void*)&cbufS, (void*)&cbufQ, (void*)&out };
    hipLaunchCooperativeKernel((const void*)qp_iter_kernel,
                               dim3(BATCH * 16), dim3(1024),
                               args, 0, stream);
}